// Round 1
// 598.056 us; speedup vs baseline: 1.0160x; 1.0160x over previous
//
#include <hip/hip_runtime.h>
#include <hip/hip_bf16.h>

#define B_ 16
#define Q_ 2048
#define S_ 2048
#define D_ 128
#define SCALE 0.08838834764831845f   // 1/sqrt(128)

typedef unsigned short ushort_t;
typedef unsigned long long u64_t;
typedef __attribute__((ext_vector_type(8))) __bf16 bf16x8;
typedef __attribute__((ext_vector_type(8))) short short8;
typedef __attribute__((ext_vector_type(4))) float floatx4;

static __device__ __forceinline__ ushort_t bf16_of_f32(float f) {
    __hip_bfloat16 h = __float2bfloat16(f);   // RNE
    return *reinterpret_cast<ushort_t*>(&h);
}
static __device__ __forceinline__ float f32_of_bf16(ushort_t u) {
    return __uint_as_float(((unsigned int)u) << 16);
}
// async global->LDS, 16B/lane, dest = wave-uniform base + lane*16 (linear)
static __device__ __forceinline__ void gload_lds16(const void* g, void* l) {
    __builtin_amdgcn_global_load_lds(
        (const __attribute__((address_space(1))) unsigned int*)g,
        (__attribute__((address_space(3))) unsigned int*)l, 16, 0, 0);
}

// ---------------------------------------------------------------------------
// flags[0] = mask elem width (1/2/4 B); flags[1] = tensor dtype (0=bf16,1=f32)
// ---------------------------------------------------------------------------
__global__ void detect_kernel(const unsigned int* __restrict__ m,
                              const unsigned int* __restrict__ q,
                              int* __restrict__ flags) {
    __shared__ int sI32, sF32, sF16, sCnt;
    int t = threadIdx.x;
    if (t == 0) { sI32 = 0; sF32 = 0; sF16 = 0; sCnt = 0; }
    __syncthreads();
    int notI32 = 0, notF32 = 0, notF16 = 0;
    for (int i = t; i < 1024; i += 256) {
        unsigned int v = m[i];
        if (v & ~1u) notI32 = 1;
        if (!(v == 0u || v == 0x3F800000u)) notF32 = 1;
        unsigned int h0 = v & 0xFFFFu, h1 = v >> 16;
        if (!(h0 == 0u || h0 == 0x3F80u || h0 == 0x3C00u)) notF16 = 1;
        if (!(h1 == 0u || h1 == 0x3F80u || h1 == 0x3C00u)) notF16 = 1;
    }
    int cnt = 0;
    for (int i = t; i < 4096; i += 256) {
        unsigned int lo = q[i] & 0xFFFFu;
        unsigned int e = (lo >> 7) & 0xFFu;
        if (lo == 0u || (e >= 100u && e <= 140u)) cnt++;
    }
    if (notI32) atomicOr(&sI32, 1);
    if (notF32) atomicOr(&sF32, 1);
    if (notF16) atomicOr(&sF16, 1);
    atomicAdd(&sCnt, cnt);
    __syncthreads();
    if (t == 0) {
        int w;
        if (!sI32)      w = 4;
        else if (!sF32) w = 4;
        else if (!sF16) w = 2;
        else            w = 1;
        flags[0] = w;
        flags[1] = (sCnt >= 3276) ? 0 : 1;
    }
}

// ---------------------------------------------------------------------------
// f32 -> bf16 streaming convert (K). No-op if tensors already bf16.
// ---------------------------------------------------------------------------
__global__ void convert_bf16_kernel(const float* __restrict__ src,
                                    const int* __restrict__ flags,
                                    ushort_t* __restrict__ dst) {
    if (flags[1] == 0) return;
    size_t i = ((size_t)blockIdx.x * 256 + threadIdx.x) * 8;
    float4 f0 = *(const float4*)(src + i);
    float4 f1 = *(const float4*)(src + i + 4);
    short8 w;
    w[0] = (short)bf16_of_f32(f0.x); w[1] = (short)bf16_of_f32(f0.y);
    w[2] = (short)bf16_of_f32(f0.z); w[3] = (short)bf16_of_f32(f0.w);
    w[4] = (short)bf16_of_f32(f1.x); w[5] = (short)bf16_of_f32(f1.y);
    w[6] = (short)bf16_of_f32(f1.z); w[7] = (short)bf16_of_f32(f1.w);
    *(short8*)(dst + i) = w;
}

// ---------------------------------------------------------------------------
// Vt[b][d][s] = bf16(V[b][s][d])
// ---------------------------------------------------------------------------
__global__ void transpose_v_kernel(const void* __restrict__ Vraw,
                                   const int* __restrict__ flags,
                                   ushort_t* __restrict__ Vt) {
    __shared__ ushort_t t[32][33];
    const int dt = flags[1];
    int b = blockIdx.z;
    int sb = blockIdx.x * 32, db = blockIdx.y * 32;
    int x = threadIdx.x, y = threadIdx.y;
    ushort_t* Vtb = Vt + (size_t)b * D_ * S_;
    if (dt == 0) {
        const ushort_t* Vb = (const ushort_t*)Vraw + (size_t)b * S_ * D_;
        #pragma unroll
        for (int i = 0; i < 32; i += 8)
            t[y + i][x] = Vb[(size_t)(sb + y + i) * D_ + db + x];
    } else {
        const float* Vb = (const float*)Vraw + (size_t)b * S_ * D_;
        #pragma unroll
        for (int i = 0; i < 32; i += 8)
            t[y + i][x] = bf16_of_f32(Vb[(size_t)(sb + y + i) * D_ + db + x]);
    }
    __syncthreads();
    #pragma unroll
    for (int i = 0; i < 32; i += 8)
        Vtb[(size_t)(db + y + i) * S_ + sb + x] = t[x][y + i];
}

// ---------------------------------------------------------------------------
// mask -> bits prepack: bits[row*32 + ch] bit j = (mask[row][ch*64+j] != 0).
// One wave per row, 4 segments of 512 cols; lane packs 8 elems -> byte,
// 3x shfl_xor OR combines 8 lanes -> u64; lane (lane&7)==0 stores.
// Removes the 67 MB mask read + ballot work from the fused kernel.
// ---------------------------------------------------------------------------
__global__ void mask_pack_kernel(const void* __restrict__ maskp,
                                 const int* __restrict__ flags,
                                 u64_t* __restrict__ bits) {
    const int mw = flags[0];
    const int lane = threadIdx.x & 63;
    const size_t row = (size_t)blockIdx.x * 4 + (threadIdx.x >> 6);
    for (int seg = 0; seg < 4; ++seg) {
        const size_t col = (size_t)seg * 512 + lane * 8;
        unsigned int b8 = 0;
        if (mw == 1) {
            u64_t v = *(const u64_t*)((const unsigned char*)maskp + row * S_ + col);
            #pragma unroll
            for (int j = 0; j < 8; ++j)
                b8 |= (unsigned int)(((v >> (8 * j)) & 0xFFull) != 0ull) << j;
        } else if (mw == 2) {
            const ushort_t* p = (const ushort_t*)maskp + row * S_ + col;
            uint4 v = *(const uint4*)p;
            const unsigned int* w = (const unsigned int*)&v;
            #pragma unroll
            for (int j = 0; j < 4; ++j) {
                b8 |= (unsigned int)((w[j] & 0xFFFFu) != 0u) << (2 * j);
                b8 |= (unsigned int)((w[j] >> 16) != 0u) << (2 * j + 1);
            }
        } else {
            const unsigned int* p = (const unsigned int*)maskp + row * S_ + col;
            uint4 v0 = *(const uint4*)p;
            uint4 v1 = *(const uint4*)(p + 4);
            const unsigned int* w0 = (const unsigned int*)&v0;
            const unsigned int* w1 = (const unsigned int*)&v1;
            #pragma unroll
            for (int j = 0; j < 4; ++j) {
                b8 |= (unsigned int)(w0[j] != 0u) << j;
                b8 |= (unsigned int)(w1[j] != 0u) << (4 + j);
            }
        }
        u64_t w = (u64_t)b8 << ((lane & 7) * 8);
        w |= __shfl_xor(w, 1);
        w |= __shfl_xor(w, 2);
        w |= __shfl_xor(w, 4);
        if ((lane & 7) == 0)
            bits[row * 32 + seg * 8 + (lane >> 3)] = w;
    }
}

// ---------------------------------------------------------------------------
// Fused attention, 512 threads = 8 waves. wave = (wg, sh): q-rows wg*16..+15,
// s-half sh. Mask comes pre-packed as bits (read-only). Both sweeps are
// double-buffered with async global_load_lds staging (linear LDS dest +
// XOR-16B-slot swizzle applied to the per-lane global SOURCE address and to
// the ds_read address — same involution both sides). ONE barrier per chunk:
// prefetch t+1 -> compute t -> barrier (compiler's vmcnt(0) drain at the
// barrier covers the in-flight loads, which were issued a full compute-phase
// earlier, so their latency is hidden).
// ---------------------------------------------------------------------------
__launch_bounds__(512, 4)
__global__ void attn_fused_kernel(const void* __restrict__ Kraw,
                                  const ushort_t* __restrict__ Kbf,
                                  const void* __restrict__ Qraw,
                                  const int* __restrict__ flags,
                                  const ushort_t* __restrict__ Vt,
                                  const u64_t* __restrict__ bits,
                                  void* __restrict__ out_base) {
    // LDS layout (75264 B): Kl[2] @0 (2x16K) | Vl[2] @32768 (2x16K)
    //   El @65536 (64x72 u16, 9216 B) | lpart @74752 (128 f32)
    // Ob (64x132 f32, 33792 B) aliases @0 (dead Kl/Vl after sweep1).
    // Sweep2 E-tiles El2[i] alias Vl[i] @32768+i*16384 (V unused in sweep2).
    __shared__ __align__(16) char smem[75264];
    ushort_t* El     = (ushort_t*)(smem + 65536);
    float*    lpart  = (float*)(smem + 74752);
    float (*Ob)[132] = (float(*)[132])smem;

    const int tid  = threadIdx.x;
    const int wave = tid >> 6;
    const int lane = tid & 63;
    const int quad = lane >> 4;
    const int c    = lane & 15;
    const int sh   = wave & 1;    // s-half
    const int wg   = wave >> 1;   // row group

    const int qt = blockIdx.x, b = blockIdx.y;
    const int q0 = qt * 64;
    const int dt = flags[1];

    const ushort_t* Kp = dt ? Kbf : (const ushort_t*)Kraw;

    ushort_t* outh  = (ushort_t*)out_base;
    float*    outf  = (float*)out_base;
    ushort_t* attnh = outh + (size_t)B_ * Q_ * D_;
    float*    attnf = outf + (size_t)B_ * Q_ * D_;

    const size_t rowbase = (size_t)b * Q_ + q0;
    const int myrow = wg * 16 + quad * 4;
    const u64_t* bb = bits + (rowbase + myrow) * 32;   // +r*32 per acc row

    // --- per-lane swizzled staging source pointers (chunk 0) ---
    // K tile: 64 rows x 256 B; LDS slot s (16 B) of row r holds global slot
    // s^(r&15). Wave issues rows (wave*2+j)*4..+3, lane=(r_in=lane>>4, s=lane&15).
    const int kg0 = wave * 8 + (lane >> 4);
    const int kg1 = wave * 8 + 4 + (lane >> 4);
    const char* kp0 = (const char*)(Kp + (size_t)b * S_ * D_) + kg0 * 256
                      + (((lane & 15) ^ (kg0 & 15)) << 4);
    const char* kp1 = (const char*)(Kp + (size_t)b * S_ * D_) + kg1 * 256
                      + (((lane & 15) ^ (kg1 & 15)) << 4);
    // V tile: 128 rows x 128 B; slot s^(r&7). Wave rows (wave*2+j)*8..+7.
    const int vg0 = wave * 16 + (lane >> 3);
    const int vg1 = wave * 16 + 8 + (lane >> 3);
    const char* vp0 = (const char*)(Vt + ((size_t)b * D_ + vg0) * S_)
                      + (((lane & 7) ^ (vg0 & 7)) << 4);
    const char* vp1 = (const char*)(Vt + ((size_t)b * D_ + vg1) * S_)
                      + (((lane & 7) ^ (vg1 & 7)) << 4);
    char* kd0 = smem + wave * 2048;            // + bi*16384
    char* kd1 = smem + wave * 2048 + 1024;
    char* vd0 = smem + 32768 + wave * 2048;
    char* vd1 = smem + 32768 + wave * 2048 + 1024;

    // Q fragments (rows wg*16+c)
    bf16x8 qf[4];
    {
        const size_t qrow = rowbase + wg * 16 + c;
        if (dt == 0) {
            const ushort_t* p = (const ushort_t*)Qraw + qrow * D_;
            #pragma unroll
            for (int kk = 0; kk < 4; ++kk)
                qf[kk] = *(const bf16x8*)(p + kk * 32 + quad * 8);
        } else {
            const float* p = (const float*)Qraw + qrow * D_;
            #pragma unroll
            for (int kk = 0; kk < 4; ++kk) {
                float4 f0 = *(const float4*)(p + kk * 32 + quad * 8);
                float4 f1 = *(const float4*)(p + kk * 32 + quad * 8 + 4);
                bf16x8 w;
                w[0] = (__bf16)f0.x; w[1] = (__bf16)f0.y;
                w[2] = (__bf16)f0.z; w[3] = (__bf16)f0.w;
                w[4] = (__bf16)f1.x; w[5] = (__bf16)f1.y;
                w[6] = (__bf16)f1.z; w[7] = (__bf16)f1.w;
                qf[kk] = w;
            }
        }
    }

    floatx4 accO[8];
    #pragma unroll
    for (int i = 0; i < 8; ++i) accO[i] = (floatx4){0.f, 0.f, 0.f, 0.f};
    float lacc[4] = {0.f, 0.f, 0.f, 0.f};

    // ---------------- sweep 1 ----------------
    // prologue: stage chunk 0 + its mask bits
    gload_lds16(kp0, kd0);
    gload_lds16(kp1, kd1);
    gload_lds16(vp0, vd0);
    gload_lds16(vp1, vd1);
    u64_t bw[4];
    #pragma unroll
    for (int r = 0; r < 4; ++r) bw[r] = bb[r * 32];
    __syncthreads();

    int cur = 0;
    for (int t = 0; t < 32; ++t) {
        const int nxt = cur ^ 1;
        if (t + 1 < 32) {   // prefetch chunk t+1 into the other buffer
            const size_t ko = (size_t)(t + 1) << 14;   // 64 rows * 256 B
            const size_t vo = (size_t)(t + 1) << 7;    // 64 cols * 2 B
            gload_lds16(kp0 + ko, kd0 + nxt * 16384);
            gload_lds16(kp1 + ko, kd1 + nxt * 16384);
            gload_lds16(vp0 + vo, vd0 + nxt * 16384);
            gload_lds16(vp1 + vo, vd1 + nxt * 16384);
        }
        const int tn = (t + 1 < 32) ? t + 1 : t;
        u64_t bwn[4];
        #pragma unroll
        for (int r = 0; r < 4; ++r) bwn[r] = bb[r * 32 + tn];

        const char* Klc = smem + cur * 16384;
        const char* Vlc = smem + 32768 + cur * 16384;

        // QK^T on this wave's 2 s-subtiles (+mask+exp -> l, El)
        #pragma unroll
        for (int sti = 0; sti < 2; ++sti) {
            const int st = sh * 2 + sti;
            const int krow = st * 16 + c;
            const int rb = (krow & 15) << 4;
            floatx4 acc = (floatx4){0.f, 0.f, 0.f, 0.f};
            #pragma unroll
            for (int kk = 0; kk < 4; ++kk) {
                bf16x8 bf = *(const bf16x8*)(Klc + krow * 256 + ((kk * 64 + quad * 16) ^ rb));
                acc = __builtin_amdgcn_mfma_f32_16x16x32_bf16(qf[kk], bf, acc, 0, 0, 0);
            }
            #pragma unroll
            for (int r = 0; r < 4; ++r) {
                bool masked = (bw[r] >> (st * 16 + c)) & 1ull;
                float e = masked ? 0.f : __expf(acc[r] * SCALE);
                lacc[r] += e;
                El[(myrow + r) * 72 + st * 16 + c] = bf16_of_f32(e);
            }
        }
        // PV on this wave's own s-half (reads only El it wrote itself)
        {
            bf16x8 af = *(const bf16x8*)(El + (wg * 16 + c) * 72 + sh * 32 + quad * 8);
            #pragma unroll
            for (int nt = 0; nt < 8; ++nt) {
                const int vrow = nt * 16 + c;
                const int vb = ((sh * 4 + quad) ^ (vrow & 7)) << 4;
                bf16x8 bv = *(const bf16x8*)(Vlc + vrow * 128 + vb);
                accO[nt] = __builtin_amdgcn_mfma_f32_16x16x32_bf16(af, bv, accO[nt], 0, 0, 0);
            }
        }
        __syncthreads();   // cur reads done; nxt loads drained (vmcnt at barrier)
        #pragma unroll
        for (int r = 0; r < 4; ++r) bw[r] = bwn[r];
        cur = nxt;
    }

    // ---- l reduction: 16 c-lanes -> lpart[sh*64 + row], then sum halves ----
    #pragma unroll
    for (int r = 0; r < 4; ++r) {
        float v = lacc[r];
        v += __shfl_xor(v, 1); v += __shfl_xor(v, 2);
        v += __shfl_xor(v, 4); v += __shfl_xor(v, 8);
        lacc[r] = v;
    }
    if (c == 0) {
        #pragma unroll
        for (int r = 0; r < 4; ++r) lpart[sh * 64 + myrow + r] = lacc[r];
    }
    __syncthreads();
    float rcpl[4];
    #pragma unroll
    for (int r = 0; r < 4; ++r)
        rcpl[r] = 1.0f / fmaxf(lpart[myrow + r] + lpart[64 + myrow + r], 1e-30f);

    // ---- O reduction across s-halves via Ob (aliases Kl/Vl) ----
    if (sh == 0) {
        #pragma unroll
        for (int r = 0; r < 4; ++r)
            #pragma unroll
            for (int nt = 0; nt < 8; ++nt)
                Ob[myrow + r][nt * 16 + c] = accO[nt][r];
    }
    __syncthreads();
    if (sh == 1) {
        #pragma unroll
        for (int r = 0; r < 4; ++r)
            #pragma unroll
            for (int nt = 0; nt < 8; ++nt)
                Ob[myrow + r][nt * 16 + c] += accO[nt][r];
    }
    __syncthreads();
    // cooperative coalesced out store: thread -> (row, 16 cols)
    {
        const int row = tid >> 3, dc = tid & 7;
        float rcp = 1.0f / fmaxf(lpart[row] + lpart[64 + row], 1e-30f);
        size_t obase = (rowbase + row) * (size_t)D_ + dc * 16;
        if (dt == 0) {
            short8 w0, w1;
            #pragma unroll
            for (int k = 0; k < 8; ++k) {
                w0[k] = (short)bf16_of_f32(Ob[row][dc * 16 + k] * rcp);
                w1[k] = (short)bf16_of_f32(Ob[row][dc * 16 + 8 + k] * rcp);
            }
            *(short8*)(outh + obase) = w0;
            *(short8*)(outh + obase + 8) = w1;
        } else {
            #pragma unroll
            for (int g = 0; g < 4; ++g) {
                float4 f;
                f.x = Ob[row][dc * 16 + g * 4 + 0] * rcp;
                f.y = Ob[row][dc * 16 + g * 4 + 1] * rcp;
                f.z = Ob[row][dc * 16 + g * 4 + 2] * rcp;
                f.w = Ob[row][dc * 16 + g * 4 + 3] * rcp;
                *(float4*)(outf + obase + g * 4) = f;
            }
        }
    }

    // ---------------- sweep 2: normalized attention ----------------
    __syncthreads();               // Ob reads done -> safe to overwrite Kl0
    gload_lds16(kp0, kd0);         // stage K chunk 0
    gload_lds16(kp1, kd1);
    u64_t bw2[4];
    #pragma unroll
    for (int r = 0; r < 4; ++r) bw2[r] = bb[r * 32];
    __syncthreads();               // Kl0 ready

    int cur2 = 0;
    for (int t = 0; t < 32; ++t) {
        const int nxt = cur2 ^ 1;
        if (t + 1 < 32) {
            const size_t ko = (size_t)(t + 1) << 14;
            gload_lds16(kp0 + ko, kd0 + nxt * 16384);
            gload_lds16(kp1 + ko, kd1 + nxt * 16384);
        }
        const int tn = (t + 1 < 32) ? t + 1 : t;
        u64_t bwn[4];
        #pragma unroll
        for (int r = 0; r < 4; ++r) bwn[r] = bb[r * 32 + tn];

        // store tile t-1 (El2[nxt]) overlapped with tile-t compute
        if (t > 0) {
            const ushort_t* E2 = (const ushort_t*)(smem + 32768 + nxt * 16384);
            const int row = tid >> 3, sc = tid & 7;
            short8 v = *(const short8*)(E2 + row * 72 + sc * 8);
            size_t gidx = (rowbase + row) * (size_t)S_ + (size_t)(t - 1) * 64 + sc * 8;
            if (dt == 0) {
                *(short8*)(attnh + gidx) = v;
            } else {
                float4 f0, f1;
                f0.x = f32_of_bf16((ushort_t)v[0]); f0.y = f32_of_bf16((ushort_t)v[1]);
                f0.z = f32_of_bf16((ushort_t)v[2]); f0.w = f32_of_bf16((ushort_t)v[3]);
                f1.x = f32_of_bf16((ushort_t)v[4]); f1.y = f32_of_bf16((ushort_t)v[5]);
                f1.z = f32_of_bf16((ushort_t)v[6]); f1.w = f32_of_bf16((ushort_t)v[7]);
                *(float4*)(attnf + gidx) = f0;
                *(float4*)(attnf + gidx + 4) = f1;
            }
        }

        const char* Klc = smem + cur2 * 16384;
        ushort_t* E2w = (ushort_t*)(smem + 32768 + cur2 * 16384);
        #pragma unroll
        for (int sti = 0; sti < 2; ++sti) {
            const int st = sh * 2 + sti;
            const int krow = st * 16 + c;
            const int rb = (krow & 15) << 4;
            floatx4 acc = (floatx4){0.f, 0.f, 0.f, 0.f};
            #pragma unroll
            for (int kk = 0; kk < 4; ++kk) {
                bf16x8 bf = *(const bf16x8*)(Klc + krow * 256 + ((kk * 64 + quad * 16) ^ rb));
                acc = __builtin_amdgcn_mfma_f32_16x16x32_bf16(qf[kk], bf, acc, 0, 0, 0);
            }
            #pragma unroll
            for (int r = 0; r < 4; ++r) {
                bool masked = (bw2[r] >> (st * 16 + c)) & 1ull;
                float e = masked ? 0.f : __expf(acc[r] * SCALE) * rcpl[r];
                E2w[(myrow + r) * 72 + st * 16 + c] = bf16_of_f32(e);
            }
        }
        __syncthreads();   // E2w complete; Kl[nxt] drained; E2[nxt] store reads done
        #pragma unroll
        for (int r = 0; r < 4; ++r) bw2[r] = bwn[r];
        cur2 = nxt;
    }
    // epilogue: store tile 31 (buffer 31&1 = 1)
    {
        const ushort_t* E2 = (const ushort_t*)(smem + 32768 + 16384);
        const int row = tid >> 3, sc = tid & 7;
        short8 v = *(const short8*)(E2 + row * 72 + sc * 8);
        size_t gidx = (rowbase + row) * (size_t)S_ + (size_t)31 * 64 + sc * 8;
        if (dt == 0) {
            *(short8*)(attnh + gidx) = v;
        } else {
            float4 f0, f1;
            f0.x = f32_of_bf16((ushort_t)v[0]); f0.y = f32_of_bf16((ushort_t)v[1]);
            f0.z = f32_of_bf16((ushort_t)v[2]); f0.w = f32_of_bf16((ushort_t)v[3]);
            f1.x = f32_of_bf16((ushort_t)v[4]); f1.y = f32_of_bf16((ushort_t)v[5]);
            f1.z = f32_of_bf16((ushort_t)v[6]); f1.w = f32_of_bf16((ushort_t)v[7]);
            *(float4*)(attnf + gidx) = f0;
            *(float4*)(attnf + gidx + 4) = f1;
        }
    }
}

extern "C" void kernel_launch(void* const* d_in, const int* in_sizes, int n_in,
                              void* d_out, int out_size, void* d_ws, size_t ws_size,
                              hipStream_t stream) {
    const void* Vraw = d_in[0];
    const void* Kraw = d_in[1];
    const void* Qraw = d_in[2];
    const void* maskp = d_in[3];

    char* ws = (char*)d_ws;
    int*  flags   = (int*)ws;                                    // 256 B
    ushort_t* Vt  = (ushort_t*)(ws + 256);                       // 8.39 MB
    u64_t* bits   = (u64_t*)(ws + 256 + 8388608);                // 8.39 MB
    ushort_t* Kbf = (ushort_t*)(ws + 256 + 2 * 8388608);         // 8.39 MB

    detect_kernel<<<1, 256, 0, stream>>>((const unsigned int*)maskp,
                                         (const unsigned int*)Qraw, flags);
    convert_bf16_kernel<<<(B_ * S_ * D_) / 2048, 256, 0, stream>>>(
        (const float*)Kraw, flags, Kbf);
    transpose_v_kernel<<<dim3(S_ / 32, D_ / 32, B_), dim3(32, 8), 0, stream>>>(
        Vraw, flags, Vt);
    mask_pack_kernel<<<(B_ * Q_) / 4, 256, 0, stream>>>(maskp, flags, bits);
    attn_fused_kernel<<<dim3(Q_ / 64, B_), 512, 0, stream>>>(
        Kraw, Kbf, Qraw, flags, Vt, bits, d_out);
}